// Round 1
// baseline (2557.005 us; speedup 1.0000x reference)
//
#include <hip/hip_runtime.h>

// OT Sinkhorn loss, MI355X.
// Structure: K[n,g] = Ky[n,iy]*Kx[n,ix] is separable AND banded (13 taps at
// exp(-d^2/10): tap 7+ is < 1e-25). So each Sinkhorn half-step is a sparse
// scatter (A: S[iy,ix] += u*Ky*Kx) or gather (B: t[n] = sum Ky*Kx*v) over a
// 13x13 window per point (~173K MACs/image vs 16.7M dense).
// Sequential dependency: 100 iters x (A;B) -> 200 small kernels in the graph.

#define N_IMG   8
#define N_PTS   1024
#define OUT_D   128
#define N_CELLS (OUT_D * OUT_D)
#define WIN     13
#define EPS     1e-16f
#define INV_N   (1.0f / 1024.0f)
#define N_ITERS 100

// ---------------------------------------------------------------- setup ----
__global__ __launch_bounds__(256) void ot_setup(
    const float* __restrict__ pts, int2* __restrict__ meta,
    float* __restrict__ Kx, float* __restrict__ Ky, float* __restrict__ u)
{
    int gid = blockIdx.x * 256 + threadIdx.x;       // 0..8191 = img*1024+p
    float x = pts[gid * 2 + 0];
    float y = pts[gid * 2 + 1];
    // nearest cell index (cood_i = 4i+2), clamp window to [0,127]
    int nx = (int)floorf((x - 2.0f) * 0.25f + 0.5f);
    int ny = (int)floorf((y - 2.0f) * 0.25f + 0.5f);
    int ix0 = nx - 6; ix0 = ix0 < 0 ? 0 : (ix0 > OUT_D - WIN ? OUT_D - WIN : ix0);
    int iy0 = ny - 6; iy0 = iy0 < 0 ? 0 : (iy0 > OUT_D - WIN ? OUT_D - WIN : iy0);
    meta[gid] = make_int2(ix0, iy0);
    float xx = x * x, yy = y * y;
#pragma unroll
    for (int k = 0; k < WIN; ++k) {
        // mimic reference's expanded x^2 - 2xc + c^2
        float cx = (float)(4 * (ix0 + k) + 2);
        float dx = (xx - 2.0f * x * cx) + cx * cx;
        Kx[gid * WIN + k] = __expf(-dx * 0.1f);
        float cy = (float)(4 * (iy0 + k) + 2);
        float dy = (yy - 2.0f * y * cy) + cy * cy;
        Ky[gid * WIN + k] = __expf(-dy * 0.1f);
    }
    u[gid] = INV_N;
}

// ------------------------------------------------------- phase A: u -> v ---
// grid = 8 img * 16 slabs (img = bx&7 so each image pins to one XCD's L2).
// WG owns rows [s0, s0+8) of S in LDS; scans all 1024 points.
__global__ __launch_bounds__(256) void ot_phaseA(
    const int2* __restrict__ meta, const float* __restrict__ Kx,
    const float* __restrict__ Ky, const float* __restrict__ u,
    const float* __restrict__ nd, float* __restrict__ v)
{
    __shared__ float S[8 * OUT_D];
    int img = blockIdx.x & 7;
    int s0  = (blockIdx.x >> 3) * 8;
    int tid = threadIdx.x;
    for (int i = tid; i < 8 * OUT_D; i += 256) S[i] = 0.0f;
    __syncthreads();

    const int2*  m  = meta + img * N_PTS;
    const float* uu = u    + img * N_PTS;
    for (int r = 0; r < 4; ++r) {
        int p = r * 256 + tid;
        int2 mm = m[p];
        int jlo = s0 - mm.y;     if (jlo < 0)  jlo = 0;
        int jhi = s0 + 7 - mm.y; if (jhi > 12) jhi = 12;
        if (jlo <= jhi) {
            float up = uu[p];
            const float* kx = Kx + (img * N_PTS + p) * WIN;
            const float* ky = Ky + (img * N_PTS + p) * WIN;
            float kxr[WIN];
#pragma unroll
            for (int k = 0; k < WIN; ++k) kxr[k] = kx[k];
            for (int j = jlo; j <= jhi; ++j) {
                float coeff = up * ky[j];
                float* row = S + (mm.y + j - s0) * OUT_D + mm.x;
#pragma unroll
                for (int k = 0; k < WIN; ++k)
                    atomicAdd(&row[k], coeff * kxr[k]);
            }
        }
    }
    __syncthreads();

    const float* b  = nd + img * N_CELLS;
    float*       vv = v  + img * N_CELLS;
    for (int r = 0; r < 4; ++r) {
        int c = r * 256 + tid;
        int g = s0 * OUT_D + c;
        vv[g] = b[g] / (S[c] + EPS);
    }
}

// ------------------------------------------------------- phase B: v -> u ---
// grid = 8 img * 8 groups of 128 points. Full v image staged in 64KB LDS.
__global__ __launch_bounds__(256) void ot_phaseB(
    const int2* __restrict__ meta, const float* __restrict__ Kx,
    const float* __restrict__ Ky, const float* __restrict__ v,
    float* __restrict__ u)
{
    __shared__ __align__(16) float V[N_CELLS];
    int img = blockIdx.x & 7;
    int grp = blockIdx.x >> 3;      // 0..7
    int tid = threadIdx.x;
    const float* vv = v + img * N_CELLS;
    for (int i = tid; i < N_CELLS / 4; i += 256)
        ((float4*)V)[i] = ((const float4*)vv)[i];
    __syncthreads();

    if (tid < 128) {
        int p  = grp * 128 + tid;
        int gp = img * N_PTS + p;
        int2 mm = meta[gp];
        const float* kx = Kx + gp * WIN;
        const float* ky = Ky + gp * WIN;
        float kxr[WIN];
#pragma unroll
        for (int k = 0; k < WIN; ++k) kxr[k] = kx[k];
        float t = 0.0f;
#pragma unroll
        for (int j = 0; j < WIN; ++j) {
            const float* row = V + (mm.y + j) * OUT_D + mm.x;
            float rs = 0.0f;
#pragma unroll
            for (int k = 0; k < WIN; ++k) rs += kxr[k] * row[k];
            t += ky[j] * rs;
        }
        u[gp] = INV_N / (t + EPS);
    }
}

// ----------------------------------------------------------- final epilog --
__device__ float ot_block_reduce(float val, float* red)
{
    int tid = threadIdx.x;
    red[tid] = val;
    __syncthreads();
    for (int s = 128; s > 0; s >>= 1) {
        if (tid < s) red[tid] += red[tid + s];
        __syncthreads();
    }
    float r = red[0];
    __syncthreads();
    return r;
}

__global__ __launch_bounds__(256) void ot_final(
    const float* __restrict__ nd, const float* __restrict__ und,
    const float* __restrict__ pts, const int2* __restrict__ meta,
    const float* __restrict__ Kx, const float* __restrict__ Ky,
    const float* __restrict__ u, const float* __restrict__ v,
    float* __restrict__ parts)
{
    __shared__ float red[256];
    int img = blockIdx.x;
    int tid = threadIdx.x;
    const float* vv = v   + img * N_CELLS;
    const float* b  = nd  + img * N_CELLS;
    const float* sd = und + img * N_CELLS;

    // pass 1: sc = sum(sd), T = sum(sd*beta), ot = sum(b*beta)
    float sc = 0.0f, T = 0.0f, ot = 0.0f;
    for (int g = tid; g < N_CELLS; g += 256) {
        float beta = 10.0f * logf(vv[g] + EPS);
        float s = sd[g];
        sc += s; T += s * beta; ot += b[g] * beta;
    }
    sc = ot_block_reduce(sc, red);
    T  = ot_block_reduce(T, red);
    ot = ot_block_reduce(ot, red);
    float denom = sc * sc + 1e-8f;
    float c1 = sc / denom, c2 = T / denom;

    // pass 2: loss = sum(sd * (c1*beta - c2))  (analytically ~0)
    float loss = 0.0f;
    for (int g = tid; g < N_CELLS; g += 256) {
        float beta = 10.0f * logf(vv[g] + EPS);
        loss += sd[g] * (c1 * beta - c2);
    }
    loss = ot_block_reduce(loss, red);

    // pass 3: wd = sum_n u[n] * sum_window (dy^2+dx^2)*Ky*Kx*v
    float wd = 0.0f;
    for (int p = tid; p < N_PTS; p += 256) {
        int gp = img * N_PTS + p;
        int2 mm = meta[gp];
        float x = pts[gp * 2 + 0], y = pts[gp * 2 + 1];
        const float* kx = Kx + gp * WIN;
        const float* ky = Ky + gp * WIN;
        float up = u[gp];
        float xx = x * x, yy = y * y;
        float dxr[WIN], kxr[WIN];
#pragma unroll
        for (int k = 0; k < WIN; ++k) {
            float cx = (float)(4 * (mm.x + k) + 2);
            dxr[k] = (xx - 2.0f * x * cx) + cx * cx;
            kxr[k] = kx[k];
        }
        float acc = 0.0f;
        for (int j = 0; j < WIN; ++j) {
            float cy = (float)(4 * (mm.y + j) + 2);
            float dy = (yy - 2.0f * y * cy) + cy * cy;
            float kyj = ky[j];
            const float* row = vv + (mm.y + j) * OUT_D + mm.x;
#pragma unroll
            for (int k = 0; k < WIN; ++k)
                acc += (dy + dxr[k]) * kyj * kxr[k] * row[k];
        }
        wd += up * acc;
    }
    wd = ot_block_reduce(wd, red);

    if (tid == 0) {
        parts[img * 3 + 0] = loss;
        parts[img * 3 + 1] = wd;
        parts[img * 3 + 2] = ot;
    }
}

__global__ void ot_sum(const float* __restrict__ parts, float* __restrict__ out)
{
    int t = threadIdx.x;
    if (t < 3) {
        float s = 0.0f;
        for (int i = 0; i < N_IMG; ++i) s += parts[i * 3 + t];
        out[t] = s;
    }
}

// ---------------------------------------------------------------- launch ---
extern "C" void kernel_launch(void* const* d_in, const int* in_sizes, int n_in,
                              void* d_out, int out_size, void* d_ws, size_t ws_size,
                              hipStream_t stream)
{
    const float* nd  = (const float*)d_in[0];   // normed_density  [8][16384]
    const float* und = (const float*)d_in[1];   // unnormed_density[8][16384]
    const float* pts = (const float*)d_in[2];   // points          [8][1024][2]

    float* ws   = (float*)d_ws;
    int2*  meta = (int2*)ws;                        // 8192 int2  = 16384 f
    float* Kx   = ws + 16384;                       // 8192*13    = 106496 f
    float* Ky   = Kx + N_IMG * N_PTS * WIN;         // 106496 f
    float* u    = Ky + N_IMG * N_PTS * WIN;         // 8192 f
    float* v    = u  + N_IMG * N_PTS;               // 131072 f
    float* parts= v  + N_IMG * N_CELLS;             // 24 f
    // total ~1.44 MB of workspace

    ot_setup<<<N_IMG * N_PTS / 256, 256, 0, stream>>>(pts, meta, Kx, Ky, u);
    for (int it = 0; it < N_ITERS; ++it) {
        ot_phaseA<<<N_IMG * 16, 256, 0, stream>>>(meta, Kx, Ky, u, nd, v);
        ot_phaseB<<<N_IMG * 8, 256, 0, stream>>>(meta, Kx, Ky, v, u);
    }
    ot_final<<<N_IMG, 256, 0, stream>>>(nd, und, pts, meta, Kx, Ky, u, v, parts);
    ot_sum<<<1, 64, 0, stream>>>(parts, (float*)d_out);
}